// Round 6
// baseline (414.190 us; speedup 1.0000x reference)
//
#include <hip/hip_runtime.h>
#include <math.h>

#define B_SZ 8
#define SEQ  4096
#define DM   64
#define DI   128
#define NH   2
#define HD   64
#define DS   128
#define DIP  514
#define CD   384
#define QC   64
#define NC   64
#define NR   (B_SZ*SEQ)
#define WPAD 576
#define ZLD  388           // zrc leading dim (elements)

typedef __attribute__((ext_vector_type(8))) short bf16x8;
typedef __attribute__((ext_vector_type(4))) float f32x4;

__device__ __forceinline__ unsigned short f2bf(float f) {
    union { float f; unsigned int u; } x; x.f = f;
    unsigned int r = x.u + 0x7fffu + ((x.u >> 16) & 1u);
    return (unsigned short)(r >> 16);
}
__device__ __forceinline__ float bf2f(unsigned short h) {
    union { unsigned int u; float f; } x; x.u = ((unsigned int)h) << 16;
    return x.f;
}
// A/B-operand frag: lane holds M[r0+(lane&15)][k0 + (lane>>4)*8 + j], row-major [m][k]
__device__ __forceinline__ bf16x8 fragld(const unsigned short* base, int r0, int k0, int ld) {
    int l = threadIdx.x & 63;
    return *(const bf16x8*)(base + (ptrdiff_t)(r0 + (l & 15)) * ld + k0 + (l >> 4) * 8);
}

// ---------------- weight pre-conversion (once per launch) ----------------
__global__ __launch_bounds__(256) void k_wcvt(const float* __restrict__ in_w,
                                              const float* __restrict__ out_w,
                                              unsigned short* __restrict__ Wb,
                                              unsigned short* __restrict__ OWb) {
    int idx = blockIdx.x * 256 + threadIdx.x;
    if (idx < 4 * WPAD * 64) {
        int l = idx / (WPAD * 64), r = idx % (WPAD * 64);
        int n = r >> 6, k = r & 63;
        float v = (n < DIP) ? in_w[(size_t)l * DIP * 64 + (size_t)n * 64 + k] : 0.f;
        Wb[idx] = f2bf(v);
    }
    if (idx < 4 * 64 * 128) OWb[idx] = f2bf(out_w[idx]);
}

// ---------------- residual stream f32 -> bf16 (layer 0 only) ----------------
__global__ __launch_bounds__(256) void k_xcvt(const float* __restrict__ X,
                                              unsigned short* __restrict__ Xb) {
    int idx = (blockIdx.x * 256 + threadIdx.x) * 4;
    float4 v = *(const float4*)(X + idx);
    uint2 p;
    p.x = f2bf(v.x) | ((unsigned int)f2bf(v.y) << 16);
    p.y = f2bf(v.z) | ((unsigned int)f2bf(v.w) << 16);
    *(uint2*)(Xb + idx) = p;
}

// ---------------- mega: in_proj GEMM + dt/cum + conv+SiLU + G/M + Y_intra + SL^T ----------------
__global__ __launch_bounds__(1024) void k_mega(
        const unsigned short* __restrict__ Xb, const unsigned short* __restrict__ Wb,
        const float* __restrict__ CW, const float* __restrict__ CB,
        const float* __restrict__ dtb, const float* __restrict__ Alog,
        const float* __restrict__ Dv,
        unsigned short* __restrict__ Zb,
        unsigned short* __restrict__ SL, unsigned short* __restrict__ CBuf,
        float* __restrict__ EB,
        float* __restrict__ TB, unsigned short* __restrict__ YBb) {
    __shared__ unsigned short zrc[68 * ZLD];      // conv cols staging [zr][0..383]
    __shared__ unsigned short sBt[128][72];
    __shared__ unsigned short sXt[128][72];
    __shared__ unsigned short uBC[2][64][136];
    __shared__ float s_cum[2][64], s_dt[2][64], s_w[2][64], s_dtraw[2][64];
    unsigned short (*sM)[64][72] = (unsigned short (*)[64][72])&uBC[0][0][0];

    int c = blockIdx.x, b = blockIdx.y;
    size_t rbase = (size_t)b * SEQ + c * QC;
    int tid = threadIdx.x;
    int wid = tid >> 6, lane = tid & 63;
    int q4 = lane >> 4, c16 = lane & 15;

    // ---- Phase G: in_proj GEMM, 156 wave-uniform tile jobs over 16 waves ----
    for (int t = wid; t < 156; t += 16) {
        int row0, col0, mode, mt, zc0 = 0;
        if (t < 32) {            // z cols 0..127 -> Zb
            mt = t >> 3; col0 = (t & 7) * 16; row0 = (int)rbase + mt * 16; mode = 0;
        } else if (t < 36) {     // dt cols 512..513 -> s_dtraw
            mt = t - 32; col0 = 512; row0 = (int)rbase + mt * 16; mode = 1;
        } else {                 // conv cols 128..511 -> zrc (incl. halo tile mt==4)
            int u = t - 36;
            mt = u / 24; int ntc = u - mt * 24;
            col0 = 128 + ntc * 16; zc0 = ntc * 16;
            row0 = (mt < 4) ? (int)rbase + mt * 16 : (int)rbase - 16;
            if (mt == 4 && c == 0) row0 = (int)rbase;   // clamp: results masked by conv l-guards
            mode = 2;
        }
        f32x4 acc = {0.f, 0.f, 0.f, 0.f};
#pragma unroll
        for (int ks = 0; ks < 2; ks++) {
            bf16x8 a = fragld(Xb, row0, ks * 32, 64);
            bf16x8 bb = fragld(Wb, col0, ks * 32, 64);
            acc = __builtin_amdgcn_mfma_f32_16x16x32_bf16(a, bb, acc, 0, 0, 0);
        }
        if (mode == 0) {
#pragma unroll
            for (int rr = 0; rr < 4; rr++) {
                float v = acc[rr];
                float vn = __shfl_xor(v, 1);
                if (!(lane & 1)) {
                    unsigned int pk = f2bf(v) | ((unsigned int)f2bf(vn) << 16);
                    *(unsigned int*)(Zb + (size_t)(row0 + q4 * 4 + rr) * DI + col0 + c16) = pk;
                }
            }
        } else if (mode == 1) {
            if (c16 < 2)
#pragma unroll
                for (int rr = 0; rr < 4; rr++)
                    s_dtraw[c16][mt * 16 + q4 * 4 + rr] = acc[rr];
        } else {
#pragma unroll
            for (int rr = 0; rr < 4; rr++) {
                int zr = (mt < 4) ? mt * 16 + q4 * 4 + rr + 3 : q4 * 4 + rr - 13;
                if (zr >= 0) zrc[zr * ZLD + zc0 + c16] = f2bf(acc[rr]);
            }
        }
    }
    __syncthreads();

    // ---- Phase A: dt, cumsum (waves 0,1) ----
    if (wid < 2) {
        int h = wid, j = lane;
        float raw = s_dtraw[h][j] + dtb[h];
        float dt = (raw > 20.f) ? raw : log1pf(__expf(raw));
        float A = -__expf(Alog[h]);
        float x = dt * A;
        for (int off = 1; off < 64; off <<= 1) {
            float o = __shfl_up(x, off);
            if (lane >= off) x += o;
        }
        float T = __shfl(x, 63);
        s_dt[h][j] = dt;
        s_cum[h][j] = x;
        s_w[h][j] = __expf(T - x) * dt;
        EB[((size_t)(b * NC + c)) * 128 + h * 64 + j] = __expf(x);
        if (j == 0) TB[(b * 2 + h) * NC + c] = __expf(T);
    }

    // ---- Phase B: conv(4)+bias+SiLU from zrc LDS; scatter to MFMA layouts ----
    size_t cbbase = ((size_t)(b * NC + c)) * 8192;
    for (int e = tid; e < 64 * 96; e += 1024) {
        int j = e / 96;
        int q = e - j * 96;
        int cc = q * 4;
        int l = c * QC + j;
        const unsigned short* zp = zrc + (j + 3) * ZLD + cc;
        uint2 a0 = *(const uint2*)zp;
        uint2 a1 = make_uint2(0, 0), a2 = make_uint2(0, 0), a3 = make_uint2(0, 0);
        if (l >= 1) a1 = *(const uint2*)(zp - ZLD);
        if (l >= 2) a2 = *(const uint2*)(zp - 2 * ZLD);
        if (l >= 3) a3 = *(const uint2*)(zp - 3 * ZLD);
        float v[4];
#pragma unroll
        for (int u = 0; u < 4; u++) {
            unsigned int w0 = (u < 2) ? a0.x : a0.y;
            unsigned int w1 = (u < 2) ? a1.x : a1.y;
            unsigned int w2 = (u < 2) ? a2.x : a2.y;
            unsigned int w3 = (u < 2) ? a3.x : a3.y;
            int sh = (u & 1) * 16;
            float r0 = bf2f((unsigned short)(w0 >> sh));
            float r1 = bf2f((unsigned short)(w1 >> sh));
            float r2 = bf2f((unsigned short)(w2 >> sh));
            float r3 = bf2f((unsigned short)(w3 >> sh));
            float4 wv = *(const float4*)(CW + (cc + u) * 4);
            float tt = CB[cc + u] + wv.w * r0 + wv.z * r1 + wv.y * r2 + wv.x * r3;
            v[u] = tt / (1.f + __expf(-tt));
        }
        if (cc < 128) {
#pragma unroll
            for (int u = 0; u < 4; u++) sXt[cc + u][j] = f2bf(v[u]);
        } else if (cc < 256) {
            int s = cc - 128;
            unsigned int p0 = f2bf(v[0]) | ((unsigned int)f2bf(v[1]) << 16);
            unsigned int p1 = f2bf(v[2]) | ((unsigned int)f2bf(v[3]) << 16);
            *(uint2*)&uBC[0][j][s] = make_uint2(p0, p1);
#pragma unroll
            for (int u = 0; u < 4; u++) sBt[s + u][j] = f2bf(v[u]);
        } else {
            int s = cc - 256;
            unsigned int p0 = f2bf(v[0]) | ((unsigned int)f2bf(v[1]) << 16);
            unsigned int p1 = f2bf(v[2]) | ((unsigned int)f2bf(v[3]) << 16);
            *(uint2*)&uBC[1][j][s] = make_uint2(p0, p1);
            *(uint2*)(CBuf + cbbase + (size_t)j * 128 + s) = make_uint2(p0, p1);
        }
    }
    __syncthreads();

    // ---- Phase C: G = C.B^T (16 tiles / 16 waves), stage in regs, overlay sM ----
    f32x4 gacc;
    {
        int it = wid >> 2, jt = wid & 3;
        f32x4 acc = {0.f, 0.f, 0.f, 0.f};
        for (int ks = 0; ks < 4; ks++) {
            bf16x8 a = fragld(&uBC[1][0][0], it * 16, ks * 32, 136);
            bf16x8 bb = fragld(&uBC[0][0][0], jt * 16, ks * 32, 136);
            acc = __builtin_amdgcn_mfma_f32_16x16x32_bf16(a, bb, acc, 0, 0, 0);
        }
        gacc = acc;
    }
    __syncthreads();
    {
        int it = wid >> 2, jt = wid & 3;
        int j = jt * 16 + c16;
        for (int rr = 0; rr < 4; rr++) {
            int i = it * 16 + q4 * 4 + rr;
            float gv = gacc[rr];
            for (int h = 0; h < 2; h++) {
                float m = 0.f;
                if (j <= i) m = gv * __expf(s_cum[h][i] - s_cum[h][j]) * s_dt[h][j];
                sM[h][i][j] = f2bf(m);
            }
        }
    }
    __syncthreads();

    // ---- Phase D1: Y_intra = M_h @ X_h + D*x (32 tiles / 16 waves) ----
#pragma unroll
    for (int u = 0; u < 2; u++) {
        int idx = wid * 2 + u;
        int h = idx >> 4, tt = idx & 15;
        int it = tt >> 2, pt = tt & 3;
        float dco = Dv[h];
        int pg = h * 64 + pt * 16 + c16;
        f32x4 acc;
        for (int rr = 0; rr < 4; rr++) {
            int i = it * 16 + q4 * 4 + rr;
            acc[rr] = dco * bf2f(sXt[pg][i]);
        }
        for (int ks = 0; ks < 2; ks++) {
            bf16x8 a = fragld(&sM[h][0][0], it * 16, ks * 32, 72);
            bf16x8 bb = fragld(&sXt[0][0], h * 64 + pt * 16, ks * 32, 72);
            acc = __builtin_amdgcn_mfma_f32_16x16x32_bf16(a, bb, acc, 0, 0, 0);
        }
        for (int rr = 0; rr < 4; rr++) {
            int i = it * 16 + q4 * 4 + rr;
            float v = acc[rr];
            float vn = __shfl_xor(v, 1);
            if (!(lane & 1)) {
                unsigned int pk = f2bf(v) | ((unsigned int)f2bf(vn) << 16);
                *(unsigned int*)(YBb + (rbase + i) * DI + pg) = pk;
            }
        }
    }
    // ---- Phase D2: SL^T[p][s] (64 tiles / 16 waves) ----
    size_t slbase = ((size_t)(b * NC + c)) * 16384;
#pragma unroll
    for (int u = 0; u < 4; u++) {
        int idx = wid * 4 + u;
        int ptl = idx >> 3, st = idx & 7;
        int h = ptl >> 2;
        f32x4 acc = {0.f, 0.f, 0.f, 0.f};
        for (int ks = 0; ks < 2; ks++) {
            int jb = ks * 32 + (lane >> 4) * 8;
            bf16x8 a = fragld(&sXt[0][0], ptl * 16, ks * 32, 72);
            bf16x8 aw;
#pragma unroll
            for (int t = 0; t < 8; t++) aw[t] = (short)f2bf(bf2f((unsigned short)a[t]) * s_w[h][jb + t]);
            bf16x8 bb = fragld(&sBt[0][0], st * 16, ks * 32, 72);
            acc = __builtin_amdgcn_mfma_f32_16x16x32_bf16(aw, bb, acc, 0, 0, 0);
        }
        int s = st * 16 + c16;
        for (int rr = 0; rr < 4; rr++) {
            int p = ptl * 16 + q4 * 4 + rr;
            float vv = acc[rr];
            float vn = __shfl_xor(vv, 1);
            if (!(lane & 1)) {
                unsigned int pk = f2bf(vv) | ((unsigned int)f2bf(vn) << 16);
                *(unsigned int*)(SL + slbase + (size_t)p * 128 + s) = pk;
            }
        }
    }
}

// ---------------- cross-chunk state scan ----------------
__global__ __launch_bounds__(256) void k_scan(unsigned short* __restrict__ SL,
                                              const float* __restrict__ TB) {
    int bid = blockIdx.x;
    int b = bid >> 6;
    int ps = (bid & 63) * 256 + threadIdx.x;
    int h = ps >> 13;
    const float* dAp = TB + (b * 2 + h) * NC;
    size_t base = (size_t)(b * NC) * 16384 + ps;
    float hacc = 0.f;
#pragma unroll 8
    for (int cc = 0; cc < NC; cc++) {
        size_t idx = base + (size_t)cc * 16384;
        float slv = bf2f(SL[idx]);
        SL[idx] = f2bf(hacc);
        hacc = hacc * dAp[cc] + slv;
    }
}

// ---------------- fused: Y_inter + gate*SiLU(z) + RMSNorm + out_proj + bf16 residual ----------------
__global__ __launch_bounds__(512, 2) void k_fused(
        const unsigned short* __restrict__ SL, const unsigned short* __restrict__ CBuf,
        const float* __restrict__ EB,
        const unsigned short* __restrict__ YBb, const unsigned short* __restrict__ Zb,
        const float* __restrict__ NW, const unsigned short* __restrict__ OWb,
        unsigned short* __restrict__ Xb, float* __restrict__ OutF, int last) {
    __shared__ __attribute__((aligned(16))) unsigned short sH[128][136];
    __shared__ __attribute__((aligned(16))) unsigned short sE[128][136];
    float* sGf = (float*)&sH[0][0];
    unsigned short (*sG)[136] = (unsigned short (*)[136])&sE[0][0];

    int c = blockIdx.x, b = blockIdx.y;
    size_t rbase = (size_t)b * SEQ + c * QC;
    int tid = threadIdx.x;
    int wid = tid >> 6, lane = tid & 63;
    size_t base = ((size_t)(b * NC + c)) * 16384;
    for (int u = 0; u < 4; u++) {
        int e = u * 512 + tid;
        int row = e >> 4, cb8 = (e & 15) * 8;
        *(uint4*)&sH[row][cb8] = *(const uint4*)(SL + base + (size_t)row * 128 + cb8);
    }
    size_t cbbase = ((size_t)(b * NC + c)) * 8192;
    size_t ebase  = ((size_t)(b * NC + c)) * 128;
    for (int u = 0; u < 2; u++) {
        int idx8 = u * 512 + tid;
        int i = idx8 >> 4, sc = (idx8 & 15) * 8;
        uint4 cv = *(const uint4*)(CBuf + cbbase + (size_t)i * 128 + sc);
        float e0 = EB[ebase + i], e1 = EB[ebase + 64 + i];
        unsigned int w[4] = {cv.x, cv.y, cv.z, cv.w};
        uint4 o0, o1;
        unsigned int* po0 = &o0.x;
        unsigned int* po1 = &o1.x;
#pragma unroll
        for (int t = 0; t < 4; t++) {
            float lo = bf2f((unsigned short)(w[t] & 0xffff));
            float hi = bf2f((unsigned short)(w[t] >> 16));
            po0[t] = f2bf(lo * e0) | ((unsigned int)f2bf(hi * e0) << 16);
            po1[t] = f2bf(lo * e1) | ((unsigned int)f2bf(hi * e1) << 16);
        }
        *(uint4*)&sE[i][sc] = o0;
        *(uint4*)&sE[64 + i][sc] = o1;
    }
    __syncthreads();
    int q4 = lane >> 4, c16 = lane & 15;

    float yv[4][4];
    int tit[4], tpg[4];
#pragma unroll
    for (int u = 0; u < 4; u++) {
        int idx = wid * 4 + u;
        int h = idx >> 4, tt = idx & 15;
        int it = tt >> 2, pt = tt & 3;
        f32x4 acc = {0.f, 0.f, 0.f, 0.f};
        for (int ks = 0; ks < 4; ks++) {
            bf16x8 a = fragld(&sE[0][0], h * 64 + it * 16, ks * 32, 136);
            bf16x8 bb = fragld(&sH[0][0], h * 64 + pt * 16, ks * 32, 136);
            acc = __builtin_amdgcn_mfma_f32_16x16x32_bf16(a, bb, acc, 0, 0, 0);
        }
        int pg = h * 64 + pt * 16 + c16;
        tit[u] = it; tpg[u] = pg;
        for (int rr = 0; rr < 4; rr++) {
            int i = it * 16 + q4 * 4 + rr;
            float y = acc[rr] + bf2f(YBb[(rbase + i) * DI + pg]);
            float z = bf2f(Zb[(rbase + i) * DI + pg]);
            yv[u][rr] = y * (z / (1.f + __expf(-z)));
        }
    }
    __syncthreads();
#pragma unroll
    for (int u = 0; u < 4; u++)
        for (int rr = 0; rr < 4; rr++) {
            int i = tit[u] * 16 + q4 * 4 + rr;
            sGf[i * 132 + tpg[u]] = yv[u][rr];
        }
    __syncthreads();
    {
        int row = tid >> 3, p0 = (tid & 7) * 16;
        float g[16];
        float ss = 0.f;
        for (int t2 = 0; t2 < 16; t2++) { g[t2] = sGf[row * 132 + p0 + t2]; ss += g[t2] * g[t2]; }
        ss += __shfl_xor(ss, 1);
        ss += __shfl_xor(ss, 2);
        ss += __shfl_xor(ss, 4);
        float rms = rsqrtf(ss * (1.f / 128.f) + 1e-5f);
        for (int t2 = 0; t2 < 16; t2 += 2) {
            unsigned int pk = f2bf(g[t2] * rms * NW[p0 + t2]) |
                              ((unsigned int)f2bf(g[t2 + 1] * rms * NW[p0 + t2 + 1]) << 16);
            *(unsigned int*)&sG[row][p0 + t2] = pk;
        }
    }
    __syncthreads();
#pragma unroll
    for (int u = 0; u < 2; u++) {
        int t = wid * 2 + u;
        int mt = t >> 2, nt = t & 3;
        f32x4 acc = {0.f, 0.f, 0.f, 0.f};
        for (int ks = 0; ks < 4; ks++) {
            bf16x8 a = fragld(&sG[0][0], mt * 16, ks * 32, 136);
            bf16x8 bb = *(const bf16x8*)(OWb + (size_t)(nt * 16 + c16) * 128 + ks * 32 + q4 * 8);
            acc = __builtin_amdgcn_mfma_f32_16x16x32_bf16(a, bb, acc, 0, 0, 0);
        }
        for (int rr = 0; rr < 4; rr++) {
            int m = mt * 16 + q4 * 4 + rr;
            int n = nt * 16 + c16;
            size_t o = (rbase + m) * DM + n;
            float v = bf2f(Xb[o]) + acc[rr];
            if (last) {
                OutF[o] = v;
            } else {
                float vn = __shfl_xor(v, 1);
                if (!(lane & 1)) {
                    unsigned int pk = f2bf(v) | ((unsigned int)f2bf(vn) << 16);
                    *(unsigned int*)(Xb + o) = pk;
                }
            }
        }
    }
}

extern "C" void kernel_launch(void* const* d_in, const int* in_sizes, int n_in,
                              void* d_out, int out_size, void* d_ws, size_t ws_size,
                              hipStream_t stream) {
    const float* x       = (const float*)d_in[0];
    const float* in_w    = (const float*)d_in[1];
    const float* conv_w  = (const float*)d_in[2];
    const float* conv_b  = (const float*)d_in[3];
    const float* dt_bias = (const float*)d_in[4];
    const float* A_log   = (const float*)d_in[5];
    const float* Dp      = (const float*)d_in[6];
    const float* norm_w  = (const float*)d_in[7];
    const float* out_w   = (const float*)d_in[8];
    float* out = (float*)d_out;
    float* ws  = (float*)d_ws;

    float* tb = ws;                                        // 1024 f32
    float* eb = tb + 1024;                                 // 8*64*128 f32
    unsigned short* zb   = (unsigned short*)(eb + (size_t)B_SZ * NC * 128); // NR*128
    unsigned short* ybb  = zb + (size_t)NR * DI;           // NR*128
    unsigned short* sl   = ybb + (size_t)NR * DI;          // 8*64*16384
    unsigned short* cbuf = sl + (size_t)B_SZ * NC * 16384; // 8*64*8192
    unsigned short* xb   = cbuf + (size_t)B_SZ * NC * 8192;// NR*64
    unsigned short* wb   = xb + (size_t)NR * DM;           // 4*576*64
    unsigned short* owb  = wb + (size_t)4 * WPAD * 64;     // 4*64*128

    k_wcvt<<<(4 * WPAD * 64 + 255) / 256, 256, 0, stream>>>(in_w, out_w, wb, owb);
    k_xcvt<<<NR * DM / 1024, 256, 0, stream>>>(x, xb);

    for (int layer = 0; layer < 4; layer++) {
        k_mega<<<dim3(NC, B_SZ), 1024, 0, stream>>>(xb, wb + (size_t)layer * WPAD * 64,
                conv_w + (size_t)layer * CD * 4, conv_b + (size_t)layer * CD,
                dt_bias + layer * NH, A_log + layer * NH, Dp + layer * NH,
                zb, sl, cbuf, eb, tb, ybb);
        k_scan<<<512, 256, 0, stream>>>(sl, tb);
        k_fused<<<dim3(NC, B_SZ), 512, 0, stream>>>(sl, cbuf, eb, ybb, zb,
                norm_w + layer * DI, owb + (size_t)layer * 64 * 128, xb, out,
                (layer == 3) ? 1 : 0);
    }
}

// Round 9
// 389.094 us; speedup vs baseline: 1.0645x; 1.0645x over previous
//
#include <hip/hip_runtime.h>
#include <math.h>

#define B_SZ 8
#define SEQ  4096
#define DM   64
#define DI   128
#define NH   2
#define HD   64
#define DS   128
#define DIP  514
#define ZW   512
#define CD   384
#define QC   64
#define NC   64
#define NR   (B_SZ*SEQ)
#define WPAD 576

typedef __attribute__((ext_vector_type(8))) short bf16x8;
typedef __attribute__((ext_vector_type(4))) float f32x4;

__device__ __forceinline__ unsigned short f2bf(float f) {
    union { float f; unsigned int u; } x; x.f = f;
    unsigned int r = x.u + 0x7fffu + ((x.u >> 16) & 1u);
    return (unsigned short)(r >> 16);
}
__device__ __forceinline__ float bf2f(unsigned short h) {
    union { unsigned int u; float f; } x; x.u = ((unsigned int)h) << 16;
    return x.f;
}
// A/B-operand frag: lane holds M[r0+(lane&15)][k0 + (lane>>4)*8 + j], row-major [m][k]
__device__ __forceinline__ bf16x8 fragld(const unsigned short* base, int r0, int k0, int ld) {
    int l = threadIdx.x & 63;
    return *(const bf16x8*)(base + (ptrdiff_t)(r0 + (l & 15)) * ld + k0 + (l >> 4) * 8);
}

// ---------------- weight pre-conversion (once per launch) ----------------
__global__ __launch_bounds__(256) void k_wcvt(const float* __restrict__ in_w,
                                              const float* __restrict__ out_w,
                                              unsigned short* __restrict__ Wb,
                                              unsigned short* __restrict__ OWb) {
    int idx = blockIdx.x * 256 + threadIdx.x;
    if (idx < 4 * WPAD * 64) {
        int l = idx / (WPAD * 64), r = idx % (WPAD * 64);
        int n = r >> 6, k = r & 63;
        float v = (n < DIP) ? in_w[(size_t)l * DIP * 64 + (size_t)n * 64 + k] : 0.f;
        Wb[idx] = f2bf(v);
    }
    if (idx < 4 * 64 * 128) OWb[idx] = f2bf(out_w[idx]);
}

// ---------------- residual stream f32 -> bf16 (layer 0 only) ----------------
__global__ __launch_bounds__(256) void k_xcvt(const float* __restrict__ X,
                                              unsigned short* __restrict__ Xb) {
    int idx = (blockIdx.x * 256 + threadIdx.x) * 4;
    float4 v = *(const float4*)(X + idx);
    uint2 p;
    p.x = f2bf(v.x) | ((unsigned int)f2bf(v.y) << 16);
    p.y = f2bf(v.z) | ((unsigned int)f2bf(v.w) << 16);
    *(uint2*)(Xb + idx) = p;
}

// ---------------- in_proj: LDS-free MFMA, bf16 in/out ----------------
__global__ __launch_bounds__(256) void k_inproj(const unsigned short* __restrict__ Xb,
                                                const unsigned short* __restrict__ Wb,
                                                unsigned short* __restrict__ ZXb,
                                                float* __restrict__ DT) {
    int m0 = blockIdx.x * 256;
    int n0 = blockIdx.y * 64;
    int tid = threadIdx.x;
    int wid = tid >> 6, lane = tid & 63;
    int q4 = lane >> 4, c16 = lane & 15;
    int mb = m0 + wid * 64;
    bf16x8 af[4][2];
#pragma unroll
    for (int mt = 0; mt < 4; mt++)
#pragma unroll
        for (int ks = 0; ks < 2; ks++)
            af[mt][ks] = *(const bf16x8*)(Xb + (size_t)(mb + mt * 16 + c16) * 64 + ks * 32 + q4 * 8);
    if (n0 < 512) {
#pragma unroll
        for (int nt = 0; nt < 4; nt++) {
            bf16x8 bf[2];
#pragma unroll
            for (int ks = 0; ks < 2; ks++)
                bf[ks] = *(const bf16x8*)(Wb + (size_t)(n0 + nt * 16 + c16) * 64 + ks * 32 + q4 * 8);
#pragma unroll
            for (int mt = 0; mt < 4; mt++) {
                f32x4 acc = {0.f, 0.f, 0.f, 0.f};
                acc = __builtin_amdgcn_mfma_f32_16x16x32_bf16(af[mt][0], bf[0], acc, 0, 0, 0);
                acc = __builtin_amdgcn_mfma_f32_16x16x32_bf16(af[mt][1], bf[1], acc, 0, 0, 0);
#pragma unroll
                for (int rr = 0; rr < 4; rr++) {
                    float v = acc[rr];
                    float vn = __shfl_xor(v, 1);
                    if (!(lane & 1)) {
                        unsigned int pk = f2bf(v) | ((unsigned int)f2bf(vn) << 16);
                        *(unsigned int*)(ZXb + (size_t)(mb + mt * 16 + q4 * 4 + rr) * ZW + n0 + nt * 16 + c16) = pk;
                    }
                }
            }
        }
    } else {
        bf16x8 bf[2];
#pragma unroll
        for (int ks = 0; ks < 2; ks++)
            bf[ks] = *(const bf16x8*)(Wb + (size_t)(512 + c16) * 64 + ks * 32 + q4 * 8);
#pragma unroll
        for (int mt = 0; mt < 4; mt++) {
            f32x4 acc = {0.f, 0.f, 0.f, 0.f};
            acc = __builtin_amdgcn_mfma_f32_16x16x32_bf16(af[mt][0], bf[0], acc, 0, 0, 0);
            acc = __builtin_amdgcn_mfma_f32_16x16x32_bf16(af[mt][1], bf[1], acc, 0, 0, 0);
            if (c16 < 2)
#pragma unroll
                for (int rr = 0; rr < 4; rr++)
                    DT[(size_t)(mb + mt * 16 + q4 * 4 + rr) * 2 + c16] = acc[rr];
        }
    }
}

// ---------------- chunk1 (1024 thr, 2 blk/CU): dt/cum, conv+SiLU, G, M, Y_intra, SL^T ----------------
__global__ __launch_bounds__(1024, 8) void k_chunk1(
        const unsigned short* __restrict__ ZXb, const float* __restrict__ DT,
        const float* __restrict__ CW, const float* __restrict__ CB,
        const float* __restrict__ dtb, const float* __restrict__ Alog,
        const float* __restrict__ Dv,
        unsigned short* __restrict__ SL, unsigned short* __restrict__ CBuf,
        float* __restrict__ EB,
        float* __restrict__ TB, unsigned short* __restrict__ YBb) {
    __shared__ unsigned short sBt[128][72];
    __shared__ unsigned short sXt[128][72];
    __shared__ unsigned short uBC[2][64][136];
    __shared__ float s_cum[2][64], s_dt[2][64], s_w[2][64];
    unsigned short (*sM)[64][72] = (unsigned short (*)[64][72])&uBC[0][0][0];

    int c = blockIdx.x, b = blockIdx.y;
    size_t rbase = (size_t)b * SEQ + c * QC;
    int tid = threadIdx.x;
    int wid = tid >> 6, lane = tid & 63;
    int q4 = lane >> 4, c16 = lane & 15;

    // Phase A: dt/cumsum (waves 0,1) — ordered vs Phase C by the conv barrier
    if (wid < 2) {
        int h = wid, j = lane;
        float raw = DT[(rbase + j) * 2 + h] + dtb[h];
        float dt = (raw > 20.f) ? raw : log1pf(__expf(raw));
        float A = -__expf(Alog[h]);
        float x = dt * A;
        for (int off = 1; off < 64; off <<= 1) {
            float o = __shfl_up(x, off);
            if (lane >= off) x += o;
        }
        float T = __shfl(x, 63);
        s_dt[h][j] = dt;
        s_cum[h][j] = x;
        s_w[h][j] = __expf(T - x) * dt;
        EB[((size_t)(b * NC + c)) * 128 + h * 64 + j] = __expf(x);
        if (j == 0) TB[(b * 2 + h) * NC + c] = __expf(T);
    }

    // Phase B: conv(4)+bias+SiLU from global ZXb; scatter to MFMA layouts
    size_t cbbase = ((size_t)(b * NC + c)) * 8192;
    for (int e = tid; e < 64 * 96; e += 1024) {
        int j = e / 96;
        int q = e - j * 96;
        int cc = q * 4;
        int l = c * QC + j;
        const unsigned short* zp = ZXb + (rbase + j) * ZW + 128 + cc;
        uint2 a0 = *(const uint2*)zp;
        uint2 a1 = make_uint2(0, 0), a2 = make_uint2(0, 0), a3 = make_uint2(0, 0);
        if (l >= 1) a1 = *(const uint2*)(zp - ZW);
        if (l >= 2) a2 = *(const uint2*)(zp - 2 * ZW);
        if (l >= 3) a3 = *(const uint2*)(zp - 3 * ZW);
        float v[4];
#pragma unroll
        for (int u = 0; u < 4; u++) {
            unsigned int w0 = (u < 2) ? a0.x : a0.y;
            unsigned int w1 = (u < 2) ? a1.x : a1.y;
            unsigned int w2 = (u < 2) ? a2.x : a2.y;
            unsigned int w3 = (u < 2) ? a3.x : a3.y;
            int sh = (u & 1) * 16;
            float r0 = bf2f((unsigned short)(w0 >> sh));
            float r1 = bf2f((unsigned short)(w1 >> sh));
            float r2 = bf2f((unsigned short)(w2 >> sh));
            float r3 = bf2f((unsigned short)(w3 >> sh));
            float4 wv = *(const float4*)(CW + (cc + u) * 4);
            float tt = CB[cc + u] + wv.w * r0 + wv.z * r1 + wv.y * r2 + wv.x * r3;
            v[u] = tt / (1.f + __expf(-tt));
        }
        if (cc < 128) {
#pragma unroll
            for (int u = 0; u < 4; u++) sXt[cc + u][j] = f2bf(v[u]);
        } else if (cc < 256) {
            int s = cc - 128;
            unsigned int p0 = f2bf(v[0]) | ((unsigned int)f2bf(v[1]) << 16);
            unsigned int p1 = f2bf(v[2]) | ((unsigned int)f2bf(v[3]) << 16);
            *(uint2*)&uBC[0][j][s] = make_uint2(p0, p1);
#pragma unroll
            for (int u = 0; u < 4; u++) sBt[s + u][j] = f2bf(v[u]);
        } else {
            int s = cc - 256;
            unsigned int p0 = f2bf(v[0]) | ((unsigned int)f2bf(v[1]) << 16);
            unsigned int p1 = f2bf(v[2]) | ((unsigned int)f2bf(v[3]) << 16);
            *(uint2*)&uBC[1][j][s] = make_uint2(p0, p1);
            *(uint2*)(CBuf + cbbase + (size_t)j * 128 + s) = make_uint2(p0, p1);
        }
    }
    __syncthreads();

    // Phase C: G = C.B^T (16 tiles / 16 waves), stage in regs, overlay sM
    f32x4 gacc;
    {
        int it = wid >> 2, jt = wid & 3;
        f32x4 acc = {0.f, 0.f, 0.f, 0.f};
        for (int ks = 0; ks < 4; ks++) {
            bf16x8 a = fragld(&uBC[1][0][0], it * 16, ks * 32, 136);
            bf16x8 bb = fragld(&uBC[0][0][0], jt * 16, ks * 32, 136);
            acc = __builtin_amdgcn_mfma_f32_16x16x32_bf16(a, bb, acc, 0, 0, 0);
        }
        gacc = acc;
    }
    __syncthreads();
    {
        int it = wid >> 2, jt = wid & 3;
        int j = jt * 16 + c16;
        for (int rr = 0; rr < 4; rr++) {
            int i = it * 16 + q4 * 4 + rr;
            float gv = gacc[rr];
            for (int h = 0; h < 2; h++) {
                float m = 0.f;
                if (j <= i) m = gv * __expf(s_cum[h][i] - s_cum[h][j]) * s_dt[h][j];
                sM[h][i][j] = f2bf(m);
            }
        }
    }
    __syncthreads();

    // Phase D1: Y_intra = M_h @ X_h + D*x (32 tiles / 16 waves)
#pragma unroll
    for (int u = 0; u < 2; u++) {
        int idx = wid * 2 + u;
        int h = idx >> 4, tt = idx & 15;
        int it = tt >> 2, pt = tt & 3;
        float dco = Dv[h];
        int pg = h * 64 + pt * 16 + c16;
        f32x4 acc;
        for (int rr = 0; rr < 4; rr++) {
            int i = it * 16 + q4 * 4 + rr;
            acc[rr] = dco * bf2f(sXt[pg][i]);
        }
        for (int ks = 0; ks < 2; ks++) {
            bf16x8 a = fragld(&sM[h][0][0], it * 16, ks * 32, 72);
            bf16x8 bb = fragld(&sXt[0][0], h * 64 + pt * 16, ks * 32, 72);
            acc = __builtin_amdgcn_mfma_f32_16x16x32_bf16(a, bb, acc, 0, 0, 0);
        }
        for (int rr = 0; rr < 4; rr++) {
            int i = it * 16 + q4 * 4 + rr;
            float v = acc[rr];
            float vn = __shfl_xor(v, 1);
            if (!(lane & 1)) {
                unsigned int pk = f2bf(v) | ((unsigned int)f2bf(vn) << 16);
                *(unsigned int*)(YBb + (rbase + i) * DI + pg) = pk;
            }
        }
    }
    // Phase D2: SL^T[p][s] (64 tiles / 16 waves)
    size_t slbase = ((size_t)(b * NC + c)) * 16384;
#pragma unroll
    for (int u = 0; u < 4; u++) {
        int idx = wid * 4 + u;
        int ptl = idx >> 3, st = idx & 7;
        int h = ptl >> 2;
        f32x4 acc = {0.f, 0.f, 0.f, 0.f};
        for (int ks = 0; ks < 2; ks++) {
            int jb = ks * 32 + (lane >> 4) * 8;
            bf16x8 a = fragld(&sXt[0][0], ptl * 16, ks * 32, 72);
            bf16x8 aw;
#pragma unroll
            for (int t = 0; t < 8; t++) aw[t] = (short)f2bf(bf2f((unsigned short)a[t]) * s_w[h][jb + t]);
            bf16x8 bb = fragld(&sBt[0][0], st * 16, ks * 32, 72);
            acc = __builtin_amdgcn_mfma_f32_16x16x32_bf16(aw, bb, acc, 0, 0, 0);
        }
        int s = st * 16 + c16;
        for (int rr = 0; rr < 4; rr++) {
            int p = ptl * 16 + q4 * 4 + rr;
            float vv = acc[rr];
            float vn = __shfl_xor(vv, 1);
            if (!(lane & 1)) {
                unsigned int pk = f2bf(vv) | ((unsigned int)f2bf(vn) << 16);
                *(unsigned int*)(SL + slbase + (size_t)p * 128 + s) = pk;
            }
        }
    }
}

// ---------------- cross-chunk state scan (uint2 vectorized, pipelined) ----------------
__global__ __launch_bounds__(128) void k_scan(unsigned short* __restrict__ SL,
                                              const float* __restrict__ TB) {
    int bid = blockIdx.x;                 // 256 blocks
    int b = bid >> 5;
    int ps = ((bid & 31) * 128 + threadIdx.x) * 4;   // 4 chains per thread
    int h = ps >> 13;
    const float* dAp = TB + (b * 2 + h) * NC;
    size_t base = (size_t)(b * NC) * 16384 + ps;
    float h0 = 0.f, h1 = 0.f, h2 = 0.f, h3 = 0.f;
    uint2 cur = *(const uint2*)(SL + base);
    for (int cc = 0; cc < NC; cc++) {
        uint2 nxt = make_uint2(0, 0);
        if (cc + 1 < NC) nxt = *(const uint2*)(SL + base + (size_t)(cc + 1) * 16384);
        float dA = dAp[cc];
        float s0 = bf2f((unsigned short)(cur.x & 0xffff));
        float s1 = bf2f((unsigned short)(cur.x >> 16));
        float s2 = bf2f((unsigned short)(cur.y & 0xffff));
        float s3 = bf2f((unsigned short)(cur.y >> 16));
        uint2 st;
        st.x = f2bf(h0) | ((unsigned int)f2bf(h1) << 16);
        st.y = f2bf(h2) | ((unsigned int)f2bf(h3) << 16);
        *(uint2*)(SL + base + (size_t)cc * 16384) = st;
        h0 = h0 * dA + s0;
        h1 = h1 * dA + s1;
        h2 = h2 * dA + s2;
        h3 = h3 * dA + s3;
        cur = nxt;
    }
}

// ---------------- fused (1024 thr, 2 blk/CU): Y_inter + gate + RMSNorm + out_proj + residual ----------------
__global__ __launch_bounds__(1024, 8) void k_fused(
        const unsigned short* __restrict__ SL, const unsigned short* __restrict__ CBuf,
        const float* __restrict__ EB,
        const unsigned short* __restrict__ YBb, const unsigned short* __restrict__ ZXb,
        const float* __restrict__ NW, const unsigned short* __restrict__ OWb,
        unsigned short* __restrict__ Xb, float* __restrict__ OutF, int last) {
    __shared__ __attribute__((aligned(16))) unsigned short sH[128][136];
    __shared__ __attribute__((aligned(16))) unsigned short sE[128][136];
    float* sGf = (float*)&sH[0][0];                                   // [64][132] overlay
    unsigned short (*sG)[136] = (unsigned short (*)[136])&sE[0][0];   // [64][136] overlay

    int c = blockIdx.x, b = blockIdx.y;
    size_t rbase = (size_t)b * SEQ + c * QC;
    int tid = threadIdx.x;
    int wid = tid >> 6, lane = tid & 63;
    size_t base = ((size_t)(b * NC + c)) * 16384;
    for (int u = 0; u < 2; u++) {
        int e = u * 1024 + tid;
        int row = e >> 4, cb8 = (e & 15) * 8;
        *(uint4*)&sH[row][cb8] = *(const uint4*)(SL + base + (size_t)row * 128 + cb8);
    }
    size_t cbbase = ((size_t)(b * NC + c)) * 8192;
    size_t ebase  = ((size_t)(b * NC + c)) * 128;
    {
        int i = tid >> 4, sc = (tid & 15) * 8;
        uint4 cv = *(const uint4*)(CBuf + cbbase + (size_t)i * 128 + sc);
        float e0 = EB[ebase + i], e1 = EB[ebase + 64 + i];
        unsigned int w[4] = {cv.x, cv.y, cv.z, cv.w};
        uint4 o0, o1;
        unsigned int* po0 = &o0.x;
        unsigned int* po1 = &o1.x;
#pragma unroll
        for (int t = 0; t < 4; t++) {
            float lo = bf2f((unsigned short)(w[t] & 0xffff));
            float hi = bf2f((unsigned short)(w[t] >> 16));
            po0[t] = f2bf(lo * e0) | ((unsigned int)f2bf(hi * e0) << 16);
            po1[t] = f2bf(lo * e1) | ((unsigned int)f2bf(hi * e1) << 16);
        }
        *(uint4*)&sE[i][sc] = o0;
        *(uint4*)&sE[64 + i][sc] = o1;
    }
    __syncthreads();
    int q4 = lane >> 4, c16 = lane & 15;

    float yv[2][4];
    int tit[2], tpg[2];
#pragma unroll
    for (int u = 0; u < 2; u++) {
        int idx = wid * 2 + u;                 // 32 tiles / 16 waves
        int h = idx >> 4, tt = idx & 15;
        int it = tt >> 2, pt = tt & 3;
        f32x4 acc = {0.f, 0.f, 0.f, 0.f};
        for (int ks = 0; ks < 4; ks++) {
            bf16x8 a = fragld(&sE[0][0], h * 64 + it * 16, ks * 32, 136);
            bf16x8 bb = fragld(&sH[0][0], h * 64 + pt * 16, ks * 32, 136);
            acc = __builtin_amdgcn_mfma_f32_16x16x32_bf16(a, bb, acc, 0, 0, 0);
        }
        int pg = h * 64 + pt * 16 + c16;
        tit[u] = it; tpg[u] = pg;
        for (int rr = 0; rr < 4; rr++) {
            int i = it * 16 + q4 * 4 + rr;
            float y = acc[rr] + bf2f(YBb[(rbase + i) * DI + pg]);
            float z = bf2f(ZXb[(rbase + i) * ZW + pg]);   // FIX: stride ZW (z cols live in zxb[·*512 + 0..127])
            yv[u][rr] = y * (z / (1.f + __expf(-z)));
        }
    }
    __syncthreads();
#pragma unroll
    for (int u = 0; u < 2; u++)
        for (int rr = 0; rr < 4; rr++) {
            int i = tit[u] * 16 + q4 * 4 + rr;
            sGf[i * 132 + tpg[u]] = yv[u][rr];
        }
    __syncthreads();
    {
        int row = tid >> 4, part = tid & 15;
        int d0 = part * 8;
        float g[8];
        float ss = 0.f;
        for (int t2 = 0; t2 < 8; t2++) { g[t2] = sGf[row * 132 + d0 + t2]; ss += g[t2] * g[t2]; }
        ss += __shfl_xor(ss, 1);
        ss += __shfl_xor(ss, 2);
        ss += __shfl_xor(ss, 4);
        ss += __shfl_xor(ss, 8);
        float rms = rsqrtf(ss * (1.f / 128.f) + 1e-5f);
        for (int t2 = 0; t2 < 8; t2 += 2) {
            unsigned int pk = f2bf(g[t2] * rms * NW[d0 + t2]) |
                              ((unsigned int)f2bf(g[t2 + 1] * rms * NW[d0 + t2 + 1]) << 16);
            *(unsigned int*)&sG[row][d0 + t2] = pk;
        }
    }
    __syncthreads();
    {
        // out_proj: 16 tiles over 16 waves (mt 0..3 × nt 0..3)
        int mt = wid >> 2, nt = wid & 3;
        f32x4 acc = {0.f, 0.f, 0.f, 0.f};
        for (int ks = 0; ks < 4; ks++) {
            bf16x8 a = fragld(&sG[0][0], mt * 16, ks * 32, 136);
            bf16x8 bb = *(const bf16x8*)(OWb + (size_t)(nt * 16 + c16) * 128 + ks * 32 + q4 * 8);
            acc = __builtin_amdgcn_mfma_f32_16x16x32_bf16(a, bb, acc, 0, 0, 0);
        }
        for (int rr = 0; rr < 4; rr++) {
            int m = mt * 16 + q4 * 4 + rr;
            int n = nt * 16 + c16;
            size_t o = (rbase + m) * DM + n;
            float v = bf2f(Xb[o]) + acc[rr];
            if (last) {
                OutF[o] = v;
            } else {
                float vn = __shfl_xor(v, 1);
                if (!(lane & 1)) {
                    unsigned int pk = f2bf(v) | ((unsigned int)f2bf(vn) << 16);
                    *(unsigned int*)(Xb + o) = pk;
                }
            }
        }
    }
}

extern "C" void kernel_launch(void* const* d_in, const int* in_sizes, int n_in,
                              void* d_out, int out_size, void* d_ws, size_t ws_size,
                              hipStream_t stream) {
    const float* x       = (const float*)d_in[0];
    const float* in_w    = (const float*)d_in[1];
    const float* conv_w  = (const float*)d_in[2];
    const float* conv_b  = (const float*)d_in[3];
    const float* dt_bias = (const float*)d_in[4];
    const float* A_log   = (const float*)d_in[5];
    const float* Dp      = (const float*)d_in[6];
    const float* norm_w  = (const float*)d_in[7];
    const float* out_w   = (const float*)d_in[8];
    float* out = (float*)d_out;
    float* ws  = (float*)d_ws;

    float* dt = ws;                                        // NR*2 f32
    float* tb = dt + (size_t)NR * 2;                       // 1024 f32
    float* eb = tb + 1024;                                 // 8*64*128 f32
    unsigned short* zxb  = (unsigned short*)(eb + (size_t)B_SZ * NC * 128);
    unsigned short* ybb  = zxb + (size_t)NR * ZW;          // NR*128
    unsigned short* sl   = ybb + (size_t)NR * DI;          // 8*64*16384
    unsigned short* cbuf = sl + (size_t)B_SZ * NC * 16384; // 8*64*8192
    unsigned short* xb   = cbuf + (size_t)B_SZ * NC * 8192;// NR*64
    unsigned short* wb   = xb + (size_t)NR * DM;           // 4*576*64
    unsigned short* owb  = wb + (size_t)4 * WPAD * 64;     // 4*64*128

    k_wcvt<<<(4 * WPAD * 64 + 255) / 256, 256, 0, stream>>>(in_w, out_w, wb, owb);
    k_xcvt<<<NR * DM / 1024, 256, 0, stream>>>(x, xb);

    for (int layer = 0; layer < 4; layer++) {
        k_inproj<<<dim3(NR / 256, 9), 256, 0, stream>>>(xb, wb + (size_t)layer * WPAD * 64, zxb, dt);
        k_chunk1<<<dim3(NC, B_SZ), 1024, 0, stream>>>(zxb, dt,
                conv_w + (size_t)layer * CD * 4, conv_b + (size_t)layer * CD,
                dt_bias + layer * NH, A_log + layer * NH, Dp + layer * NH,
                sl, cbuf, eb, tb, ybb);
        k_scan<<<256, 128, 0, stream>>>(sl, tb);
        k_fused<<<dim3(NC, B_SZ), 1024, 0, stream>>>(sl, cbuf, eb, ybb,
                zxb, norm_w + layer * DI, owb + (size_t)layer * 64 * 128, xb, out,
                (layer == 3) ? 1 : 0);
    }
}

// Round 10
// 357.775 us; speedup vs baseline: 1.1577x; 1.0875x over previous
//
#include <hip/hip_runtime.h>
#include <math.h>

#define B_SZ 8
#define SEQ  4096
#define DM   64
#define DI   128
#define NH   2
#define HD   64
#define DS   128
#define DIP  514
#define XW   384           // zxb width: xBC only (z computed in k_fused, dt in DT)
#define CD   384
#define QC   64
#define NC   64
#define NR   (B_SZ*SEQ)
#define WPAD 576

typedef __attribute__((ext_vector_type(8))) short bf16x8;
typedef __attribute__((ext_vector_type(4))) float f32x4;

__device__ __forceinline__ unsigned short f2bf(float f) {
    union { float f; unsigned int u; } x; x.f = f;
    unsigned int r = x.u + 0x7fffu + ((x.u >> 16) & 1u);
    return (unsigned short)(r >> 16);
}
__device__ __forceinline__ float bf2f(unsigned short h) {
    union { unsigned int u; float f; } x; x.u = ((unsigned int)h) << 16;
    return x.f;
}
// A/B-operand frag: lane holds M[r0+(lane&15)][k0 + (lane>>4)*8 + j], row-major [m][k]
__device__ __forceinline__ bf16x8 fragld(const unsigned short* base, int r0, int k0, int ld) {
    int l = threadIdx.x & 63;
    return *(const bf16x8*)(base + (ptrdiff_t)(r0 + (l & 15)) * ld + k0 + (l >> 4) * 8);
}

// ---------------- weight pre-conversion (once per launch) ----------------
__global__ __launch_bounds__(256) void k_wcvt(const float* __restrict__ in_w,
                                              const float* __restrict__ out_w,
                                              unsigned short* __restrict__ Wb,
                                              unsigned short* __restrict__ OWb) {
    int idx = blockIdx.x * 256 + threadIdx.x;
    if (idx < 4 * WPAD * 64) {
        int l = idx / (WPAD * 64), r = idx % (WPAD * 64);
        int n = r >> 6, k = r & 63;
        float v = (n < DIP) ? in_w[(size_t)l * DIP * 64 + (size_t)n * 64 + k] : 0.f;
        Wb[idx] = f2bf(v);
    }
    if (idx < 4 * 64 * 128) OWb[idx] = f2bf(out_w[idx]);
}

// ---------------- residual stream f32 -> bf16 (layer 0 only) ----------------
__global__ __launch_bounds__(256) void k_xcvt(const float* __restrict__ X,
                                              unsigned short* __restrict__ Xb) {
    int idx = (blockIdx.x * 256 + threadIdx.x) * 4;
    float4 v = *(const float4*)(X + idx);
    uint2 p;
    p.x = f2bf(v.x) | ((unsigned int)f2bf(v.y) << 16);
    p.y = f2bf(v.z) | ((unsigned int)f2bf(v.w) << 16);
    *(uint2*)(Xb + idx) = p;
}

// ---------------- in_proj (xBC + dt only): LDS-free MFMA ----------------
__global__ __launch_bounds__(256) void k_inproj(const unsigned short* __restrict__ Xb,
                                                const unsigned short* __restrict__ Wb,
                                                unsigned short* __restrict__ ZXb,
                                                float* __restrict__ DT) {
    int m0 = blockIdx.x * 256;
    int ny = blockIdx.y;               // 0..5: xBC cols; 6: dt
    int tid = threadIdx.x;
    int wid = tid >> 6, lane = tid & 63;
    int q4 = lane >> 4, c16 = lane & 15;
    int mb = m0 + wid * 64;
    bf16x8 af[4][2];
#pragma unroll
    for (int mt = 0; mt < 4; mt++)
#pragma unroll
        for (int ks = 0; ks < 2; ks++)
            af[mt][ks] = *(const bf16x8*)(Xb + (size_t)(mb + mt * 16 + c16) * 64 + ks * 32 + q4 * 8);
    if (ny < 6) {
#pragma unroll
        for (int nt = 0; nt < 4; nt++) {
            bf16x8 bf[2];
#pragma unroll
            for (int ks = 0; ks < 2; ks++)
                bf[ks] = *(const bf16x8*)(Wb + (size_t)(128 + ny * 64 + nt * 16 + c16) * 64 + ks * 32 + q4 * 8);
#pragma unroll
            for (int mt = 0; mt < 4; mt++) {
                f32x4 acc = {0.f, 0.f, 0.f, 0.f};
                acc = __builtin_amdgcn_mfma_f32_16x16x32_bf16(af[mt][0], bf[0], acc, 0, 0, 0);
                acc = __builtin_amdgcn_mfma_f32_16x16x32_bf16(af[mt][1], bf[1], acc, 0, 0, 0);
#pragma unroll
                for (int rr = 0; rr < 4; rr++) {
                    float v = acc[rr];
                    float vn = __shfl_xor(v, 1);
                    if (!(lane & 1)) {
                        unsigned int pk = f2bf(v) | ((unsigned int)f2bf(vn) << 16);
                        *(unsigned int*)(ZXb + (size_t)(mb + mt * 16 + q4 * 4 + rr) * XW + ny * 64 + nt * 16 + c16) = pk;
                    }
                }
            }
        }
    } else {
        bf16x8 bf[2];
#pragma unroll
        for (int ks = 0; ks < 2; ks++)
            bf[ks] = *(const bf16x8*)(Wb + (size_t)(512 + c16) * 64 + ks * 32 + q4 * 8);
#pragma unroll
        for (int mt = 0; mt < 4; mt++) {
            f32x4 acc = {0.f, 0.f, 0.f, 0.f};
            acc = __builtin_amdgcn_mfma_f32_16x16x32_bf16(af[mt][0], bf[0], acc, 0, 0, 0);
            acc = __builtin_amdgcn_mfma_f32_16x16x32_bf16(af[mt][1], bf[1], acc, 0, 0, 0);
            if (c16 < 2)
#pragma unroll
                for (int rr = 0; rr < 4; rr++)
                    DT[(size_t)(mb + mt * 16 + q4 * 4 + rr) * 2 + c16] = acc[rr];
        }
    }
}

// ---------------- chunk1 (1024 thr): dt/cum, conv+SiLU, G, M, Y_intra, SL^T ----------------
__global__ __launch_bounds__(1024, 8) void k_chunk1(
        const unsigned short* __restrict__ ZXb, const float* __restrict__ DT,
        const float* __restrict__ CW, const float* __restrict__ CB,
        const float* __restrict__ dtb, const float* __restrict__ Alog,
        const float* __restrict__ Dv,
        unsigned short* __restrict__ SL, unsigned short* __restrict__ CBuf,
        float* __restrict__ EB,
        float* __restrict__ TB, unsigned short* __restrict__ YBb) {
    __shared__ unsigned short sBt[128][72];
    __shared__ unsigned short sXt[128][72];
    __shared__ unsigned short uBC[2][64][136];
    __shared__ float s_cum[2][64], s_dt[2][64], s_w[2][64];
    unsigned short (*sM)[64][72] = (unsigned short (*)[64][72])&uBC[0][0][0];

    int c = blockIdx.x, b = blockIdx.y;
    size_t rbase = (size_t)b * SEQ + c * QC;
    int tid = threadIdx.x;
    int wid = tid >> 6, lane = tid & 63;
    int q4 = lane >> 4, c16 = lane & 15;

    // Phase A: dt/cumsum (waves 0,1) — ordered vs Phase C by the conv barrier
    if (wid < 2) {
        int h = wid, j = lane;
        float raw = DT[(rbase + j) * 2 + h] + dtb[h];
        float dt = (raw > 20.f) ? raw : log1pf(__expf(raw));
        float A = -__expf(Alog[h]);
        float x = dt * A;
        for (int off = 1; off < 64; off <<= 1) {
            float o = __shfl_up(x, off);
            if (lane >= off) x += o;
        }
        float T = __shfl(x, 63);
        s_dt[h][j] = dt;
        s_cum[h][j] = x;
        s_w[h][j] = __expf(T - x) * dt;
        EB[((size_t)(b * NC + c)) * 128 + h * 64 + j] = __expf(x);
        if (j == 0) TB[(b * 2 + h) * NC + c] = __expf(T);
    }

    // Phase B: conv(4)+bias+SiLU from global ZXb (width 384); scatter to MFMA layouts
    size_t cbbase = ((size_t)(b * NC + c)) * 8192;
    for (int e = tid; e < 64 * 96; e += 1024) {
        int j = e / 96;
        int q = e - j * 96;
        int cc = q * 4;
        int l = c * QC + j;
        const unsigned short* zp = ZXb + (rbase + j) * XW + cc;
        uint2 a0 = *(const uint2*)zp;
        uint2 a1 = make_uint2(0, 0), a2 = make_uint2(0, 0), a3 = make_uint2(0, 0);
        if (l >= 1) a1 = *(const uint2*)(zp - XW);
        if (l >= 2) a2 = *(const uint2*)(zp - 2 * XW);
        if (l >= 3) a3 = *(const uint2*)(zp - 3 * XW);
        float v[4];
#pragma unroll
        for (int u = 0; u < 4; u++) {
            unsigned int w0 = (u < 2) ? a0.x : a0.y;
            unsigned int w1 = (u < 2) ? a1.x : a1.y;
            unsigned int w2 = (u < 2) ? a2.x : a2.y;
            unsigned int w3 = (u < 2) ? a3.x : a3.y;
            int sh = (u & 1) * 16;
            float r0 = bf2f((unsigned short)(w0 >> sh));
            float r1 = bf2f((unsigned short)(w1 >> sh));
            float r2 = bf2f((unsigned short)(w2 >> sh));
            float r3 = bf2f((unsigned short)(w3 >> sh));
            float4 wv = *(const float4*)(CW + (cc + u) * 4);
            float tt = CB[cc + u] + wv.w * r0 + wv.z * r1 + wv.y * r2 + wv.x * r3;
            v[u] = tt / (1.f + __expf(-tt));
        }
        if (cc < 128) {
#pragma unroll
            for (int u = 0; u < 4; u++) sXt[cc + u][j] = f2bf(v[u]);
        } else if (cc < 256) {
            int s = cc - 128;
            unsigned int p0 = f2bf(v[0]) | ((unsigned int)f2bf(v[1]) << 16);
            unsigned int p1 = f2bf(v[2]) | ((unsigned int)f2bf(v[3]) << 16);
            *(uint2*)&uBC[0][j][s] = make_uint2(p0, p1);
#pragma unroll
            for (int u = 0; u < 4; u++) sBt[s + u][j] = f2bf(v[u]);
        } else {
            int s = cc - 256;
            unsigned int p0 = f2bf(v[0]) | ((unsigned int)f2bf(v[1]) << 16);
            unsigned int p1 = f2bf(v[2]) | ((unsigned int)f2bf(v[3]) << 16);
            *(uint2*)&uBC[1][j][s] = make_uint2(p0, p1);
            *(uint2*)(CBuf + cbbase + (size_t)j * 128 + s) = make_uint2(p0, p1);
        }
    }
    __syncthreads();

    // Phase C: G = C.B^T (16 tiles / 16 waves), stage in regs, overlay sM
    f32x4 gacc;
    {
        int it = wid >> 2, jt = wid & 3;
        f32x4 acc = {0.f, 0.f, 0.f, 0.f};
        for (int ks = 0; ks < 4; ks++) {
            bf16x8 a = fragld(&uBC[1][0][0], it * 16, ks * 32, 136);
            bf16x8 bb = fragld(&uBC[0][0][0], jt * 16, ks * 32, 136);
            acc = __builtin_amdgcn_mfma_f32_16x16x32_bf16(a, bb, acc, 0, 0, 0);
        }
        gacc = acc;
    }
    __syncthreads();
    {
        int it = wid >> 2, jt = wid & 3;
        int j = jt * 16 + c16;
        for (int rr = 0; rr < 4; rr++) {
            int i = it * 16 + q4 * 4 + rr;
            float gv = gacc[rr];
            for (int h = 0; h < 2; h++) {
                float m = 0.f;
                if (j <= i) m = gv * __expf(s_cum[h][i] - s_cum[h][j]) * s_dt[h][j];
                sM[h][i][j] = f2bf(m);
            }
        }
    }
    __syncthreads();

    // Phase D1: Y_intra = M_h @ X_h + D*x (32 tiles / 16 waves)
#pragma unroll
    for (int u = 0; u < 2; u++) {
        int idx = wid * 2 + u;
        int h = idx >> 4, tt = idx & 15;
        int it = tt >> 2, pt = tt & 3;
        float dco = Dv[h];
        int pg = h * 64 + pt * 16 + c16;
        f32x4 acc;
        for (int rr = 0; rr < 4; rr++) {
            int i = it * 16 + q4 * 4 + rr;
            acc[rr] = dco * bf2f(sXt[pg][i]);
        }
        for (int ks = 0; ks < 2; ks++) {
            bf16x8 a = fragld(&sM[h][0][0], it * 16, ks * 32, 72);
            bf16x8 bb = fragld(&sXt[0][0], h * 64 + pt * 16, ks * 32, 72);
            acc = __builtin_amdgcn_mfma_f32_16x16x32_bf16(a, bb, acc, 0, 0, 0);
        }
        for (int rr = 0; rr < 4; rr++) {
            int i = it * 16 + q4 * 4 + rr;
            float v = acc[rr];
            float vn = __shfl_xor(v, 1);
            if (!(lane & 1)) {
                unsigned int pk = f2bf(v) | ((unsigned int)f2bf(vn) << 16);
                *(unsigned int*)(YBb + (rbase + i) * DI + pg) = pk;
            }
        }
    }
    // Phase D2: SL^T[p][s] (64 tiles / 16 waves)
    size_t slbase = ((size_t)(b * NC + c)) * 16384;
#pragma unroll
    for (int u = 0; u < 4; u++) {
        int idx = wid * 4 + u;
        int ptl = idx >> 3, st = idx & 7;
        int h = ptl >> 2;
        f32x4 acc = {0.f, 0.f, 0.f, 0.f};
        for (int ks = 0; ks < 2; ks++) {
            int jb = ks * 32 + (lane >> 4) * 8;
            bf16x8 a = fragld(&sXt[0][0], ptl * 16, ks * 32, 72);
            bf16x8 aw;
#pragma unroll
            for (int t = 0; t < 8; t++) aw[t] = (short)f2bf(bf2f((unsigned short)a[t]) * s_w[h][jb + t]);
            bf16x8 bb = fragld(&sBt[0][0], st * 16, ks * 32, 72);
            acc = __builtin_amdgcn_mfma_f32_16x16x32_bf16(aw, bb, acc, 0, 0, 0);
        }
        int s = st * 16 + c16;
        for (int rr = 0; rr < 4; rr++) {
            int p = ptl * 16 + q4 * 4 + rr;
            float vv = acc[rr];
            float vn = __shfl_xor(vv, 1);
            if (!(lane & 1)) {
                unsigned int pk = f2bf(vv) | ((unsigned int)f2bf(vn) << 16);
                *(unsigned int*)(SL + slbase + (size_t)p * 128 + s) = pk;
            }
        }
    }
}

// ---------------- cross-chunk state scan (R5 form: 512 blk x 256 thr) ----------------
__global__ __launch_bounds__(256) void k_scan(unsigned short* __restrict__ SL,
                                              const float* __restrict__ TB) {
    int bid = blockIdx.x;
    int b = bid >> 6;
    int ps = (bid & 63) * 256 + threadIdx.x;
    int h = ps >> 13;
    const float* dAp = TB + (b * 2 + h) * NC;
    size_t base = (size_t)(b * NC) * 16384 + ps;
    float hacc = 0.f;
#pragma unroll 8
    for (int cc = 0; cc < NC; cc++) {
        size_t idx = base + (size_t)cc * 16384;
        float slv = bf2f(SL[idx]);
        SL[idx] = f2bf(hacc);
        hacc = hacc * dAp[cc] + slv;
    }
}

// ---------------- fused (1024 thr): z-GEMM + Y_inter + gate + RMSNorm + out_proj + residual ----------------
__global__ __launch_bounds__(1024, 8) void k_fused(
        const unsigned short* __restrict__ SL, const unsigned short* __restrict__ CBuf,
        const float* __restrict__ EB,
        const unsigned short* __restrict__ YBb, const unsigned short* __restrict__ Wzb,
        const float* __restrict__ NW, const unsigned short* __restrict__ OWb,
        unsigned short* __restrict__ Xb, float* __restrict__ OutF, int last) {
    __shared__ __attribute__((aligned(16))) unsigned short sH[128][136];
    __shared__ __attribute__((aligned(16))) unsigned short sE[128][136];
    float* sGf = (float*)&sH[0][0];                                   // [64][132] overlay
    unsigned short (*sG)[136] = (unsigned short (*)[136])&sE[0][0];   // [64][136] overlay

    int c = blockIdx.x, b = blockIdx.y;
    size_t rbase = (size_t)b * SEQ + c * QC;
    int tid = threadIdx.x;
    int wid = tid >> 6, lane = tid & 63;
    size_t base = ((size_t)(b * NC + c)) * 16384;
    for (int u = 0; u < 2; u++) {
        int e = u * 1024 + tid;
        int row = e >> 4, cb8 = (e & 15) * 8;
        *(uint4*)&sH[row][cb8] = *(const uint4*)(SL + base + (size_t)row * 128 + cb8);
    }
    size_t cbbase = ((size_t)(b * NC + c)) * 8192;
    size_t ebase  = ((size_t)(b * NC + c)) * 128;
    {
        int i = tid >> 4, sc = (tid & 15) * 8;
        uint4 cv = *(const uint4*)(CBuf + cbbase + (size_t)i * 128 + sc);
        float e0 = EB[ebase + i], e1 = EB[ebase + 64 + i];
        unsigned int w[4] = {cv.x, cv.y, cv.z, cv.w};
        uint4 o0, o1;
        unsigned int* po0 = &o0.x;
        unsigned int* po1 = &o1.x;
#pragma unroll
        for (int t = 0; t < 4; t++) {
            float lo = bf2f((unsigned short)(w[t] & 0xffff));
            float hi = bf2f((unsigned short)(w[t] >> 16));
            po0[t] = f2bf(lo * e0) | ((unsigned int)f2bf(hi * e0) << 16);
            po1[t] = f2bf(lo * e1) | ((unsigned int)f2bf(hi * e1) << 16);
        }
        *(uint4*)&sE[i][sc] = o0;
        *(uint4*)&sE[64 + i][sc] = o1;
    }
    __syncthreads();
    int q4 = lane >> 4, c16 = lane & 15;

    float yv[2][4];
    int tit[2], tpg[2];
#pragma unroll
    for (int u = 0; u < 2; u++) {
        int idx = wid * 2 + u;                 // 32 tiles / 16 waves
        int h = idx >> 4, tt = idx & 15;
        int it = tt >> 2, pt = tt & 3;
        int pg = h * 64 + pt * 16 + c16;
        // z = Xb . Wz^T  (rows rbase+it*16.., Wz rows = gate channels pg)
        f32x4 zacc = {0.f, 0.f, 0.f, 0.f};
        // Y_inter = eC . H
        f32x4 acc = {0.f, 0.f, 0.f, 0.f};
#pragma unroll
        for (int ks = 0; ks < 2; ks++) {
            bf16x8 xa = fragld(Xb, (int)rbase + it * 16, ks * 32, 64);
            bf16x8 wz = fragld(Wzb, h * 64 + pt * 16, ks * 32, 64);
            zacc = __builtin_amdgcn_mfma_f32_16x16x32_bf16(xa, wz, zacc, 0, 0, 0);
        }
        for (int ks = 0; ks < 4; ks++) {
            bf16x8 a = fragld(&sE[0][0], h * 64 + it * 16, ks * 32, 136);
            bf16x8 bb = fragld(&sH[0][0], h * 64 + pt * 16, ks * 32, 136);
            acc = __builtin_amdgcn_mfma_f32_16x16x32_bf16(a, bb, acc, 0, 0, 0);
        }
        tit[u] = it; tpg[u] = pg;
        for (int rr = 0; rr < 4; rr++) {
            int i = it * 16 + q4 * 4 + rr;
            float y = acc[rr] + bf2f(YBb[(rbase + i) * DI + pg]);
            float z = zacc[rr];
            yv[u][rr] = y * (z / (1.f + __expf(-z)));
        }
    }
    __syncthreads();
#pragma unroll
    for (int u = 0; u < 2; u++)
        for (int rr = 0; rr < 4; rr++) {
            int i = tit[u] * 16 + q4 * 4 + rr;
            sGf[i * 132 + tpg[u]] = yv[u][rr];
        }
    __syncthreads();
    {
        int row = tid >> 4, part = tid & 15;
        int d0 = part * 8;
        float g[8];
        float ss = 0.f;
        for (int t2 = 0; t2 < 8; t2++) { g[t2] = sGf[row * 132 + d0 + t2]; ss += g[t2] * g[t2]; }
        ss += __shfl_xor(ss, 1);
        ss += __shfl_xor(ss, 2);
        ss += __shfl_xor(ss, 4);
        ss += __shfl_xor(ss, 8);
        float rms = rsqrtf(ss * (1.f / 128.f) + 1e-5f);
        for (int t2 = 0; t2 < 8; t2 += 2) {
            unsigned int pk = f2bf(g[t2] * rms * NW[d0 + t2]) |
                              ((unsigned int)f2bf(g[t2 + 1] * rms * NW[d0 + t2 + 1]) << 16);
            *(unsigned int*)&sG[row][d0 + t2] = pk;
        }
    }
    __syncthreads();
    {
        // out_proj: 16 tiles over 16 waves (mt 0..3 × nt 0..3)
        int mt = wid >> 2, nt = wid & 3;
        f32x4 acc = {0.f, 0.f, 0.f, 0.f};
        for (int ks = 0; ks < 4; ks++) {
            bf16x8 a = fragld(&sG[0][0], mt * 16, ks * 32, 136);
            bf16x8 bb = *(const bf16x8*)(OWb + (size_t)(nt * 16 + c16) * 128 + ks * 32 + q4 * 8);
            acc = __builtin_amdgcn_mfma_f32_16x16x32_bf16(a, bb, acc, 0, 0, 0);
        }
        for (int rr = 0; rr < 4; rr++) {
            int m = mt * 16 + q4 * 4 + rr;
            int n = nt * 16 + c16;
            size_t o = (rbase + m) * DM + n;
            float v = bf2f(Xb[o]) + acc[rr];
            if (last) {
                OutF[o] = v;
            } else {
                float vn = __shfl_xor(v, 1);
                if (!(lane & 1)) {
                    unsigned int pk = f2bf(v) | ((unsigned int)f2bf(vn) << 16);
                    *(unsigned int*)(Xb + o) = pk;
                }
            }
        }
    }
}

extern "C" void kernel_launch(void* const* d_in, const int* in_sizes, int n_in,
                              void* d_out, int out_size, void* d_ws, size_t ws_size,
                              hipStream_t stream) {
    const float* x       = (const float*)d_in[0];
    const float* in_w    = (const float*)d_in[1];
    const float* conv_w  = (const float*)d_in[2];
    const float* conv_b  = (const float*)d_in[3];
    const float* dt_bias = (const float*)d_in[4];
    const float* A_log   = (const float*)d_in[5];
    const float* Dp      = (const float*)d_in[6];
    const float* norm_w  = (const float*)d_in[7];
    const float* out_w   = (const float*)d_in[8];
    float* out = (float*)d_out;
    float* ws  = (float*)d_ws;

    float* dt = ws;                                        // NR*2 f32
    float* tb = dt + (size_t)NR * 2;                       // 1024 f32
    float* eb = tb + 1024;                                 // 8*64*128 f32
    unsigned short* zxb  = (unsigned short*)(eb + (size_t)B_SZ * NC * 128); // NR*384
    unsigned short* ybb  = zxb + (size_t)NR * XW;          // NR*128
    unsigned short* sl   = ybb + (size_t)NR * DI;          // 8*64*16384
    unsigned short* cbuf = sl + (size_t)B_SZ * NC * 16384; // 8*64*8192
    unsigned short* xb   = cbuf + (size_t)B_SZ * NC * 8192;// NR*64
    unsigned short* wb   = xb + (size_t)NR * DM;           // 4*576*64
    unsigned short* owb  = wb + (size_t)4 * WPAD * 64;     // 4*64*128

    k_wcvt<<<(4 * WPAD * 64 + 255) / 256, 256, 0, stream>>>(in_w, out_w, wb, owb);
    k_xcvt<<<NR * DM / 1024, 256, 0, stream>>>(x, xb);

    for (int layer = 0; layer < 4; layer++) {
        k_inproj<<<dim3(NR / 256, 7), 256, 0, stream>>>(xb, wb + (size_t)layer * WPAD * 64, zxb, dt);
        k_chunk1<<<dim3(NC, B_SZ), 1024, 0, stream>>>(zxb, dt,
                conv_w + (size_t)layer * CD * 4, conv_b + (size_t)layer * CD,
                dt_bias + layer * NH, A_log + layer * NH, Dp + layer * NH,
                sl, cbuf, eb, tb, ybb);
        k_scan<<<512, 256, 0, stream>>>(sl, tb);
        k_fused<<<dim3(NC, B_SZ), 1024, 0, stream>>>(sl, cbuf, eb, ybb,
                wb + (size_t)layer * WPAD * 64, norm_w + layer * DI,
                owb + (size_t)layer * 64 * 128, xb, out,
                (layer == 3) ? 1 : 0);
    }
}